// Round 1
// baseline (391.757 us; speedup 1.0000x reference)
//
#include <hip/hip_runtime.h>
#include <math.h>

// Problem constants
#define N_LEN 16384
#define NMODES 64
#define NROWS 1024          // B*C = 32*32
#define TWO_PI_OVER_N 3.8349519697141029e-04f

// ws layout (in floats)
#define T_OFF   0                         // T[n][k], 16384*64
#define TT_OFF  (N_LEN * NMODES)          // Tt[k][n], 64*16384
#define XM_OFF  (2 * N_LEN * NMODES)      // xm[row][k], 1024*64
#define Z_OFF   (XM_OFF + NROWS * NMODES) // z[row][k], 1024*64

// ---------------------------------------------------------------------------
// Build cas tables: T[n][k] = cas(2*pi*n*k/N), Tt[k][n] = same, transposed.
// Both stored with coalesced writes (recompute sincos for the transpose).
// ---------------------------------------------------------------------------
__global__ __launch_bounds__(256) void build_tables(float* __restrict__ ws) {
    int idx = blockIdx.x * 256 + threadIdx.x;   // 0 .. 2*1048576-1
    float* T  = ws + T_OFF;
    float* Tt = ws + TT_OFF;
    if (idx < N_LEN * NMODES) {
        int n = idx >> 6, k = idx & 63;
        int r = (n * k) & (N_LEN - 1);
        float th = (float)r * TWO_PI_OVER_N;
        float s, c;
        sincosf(th, &s, &c);
        T[idx] = c + s;
    } else {
        int j = idx - N_LEN * NMODES;
        int k = j >> 14, n = j & (N_LEN - 1);
        int r = (n * k) & (N_LEN - 1);
        float th = (float)r * TWO_PI_OVER_N;
        float s, c;
        sincosf(th, &s, &c);
        Tt[j] = c + s;
    }
}

// ---------------------------------------------------------------------------
// GEMM1: xm[row][k] += sum_n x[row][n] * T[n][k]
// lanes = k (64 modes). Each wave owns 8 rows; x values are wave-uniform ->
// scalar loads. Grid: (32 row groups of 32 rows) x (32 K-chunks of 512).
// Partial sums combined with fp32 atomicAdd (xm zeroed beforehand).
// ---------------------------------------------------------------------------
#define G1_KS 32
#define G1_NC (N_LEN / G1_KS)   // 512

__global__ __launch_bounds__(256) void gemm1(const float* __restrict__ x,
                                             const float* __restrict__ T,
                                             float* __restrict__ xm) {
    int lane = threadIdx.x & 63;
    int wave = (int)__builtin_amdgcn_readfirstlane((int)(threadIdx.x >> 6));
    int row0 = blockIdx.x * 32 + wave * 8;          // 8 rows for this wave
    int n0   = blockIdx.y * G1_NC;

    float acc[8] = {0.f, 0.f, 0.f, 0.f, 0.f, 0.f, 0.f, 0.f};
    const float* xp = x + (size_t)row0 * N_LEN + n0;  // uniform base
    const float* Tp = T + (size_t)n0 * NMODES + lane;

#pragma unroll 4
    for (int n = 0; n < G1_NC; ++n) {
        float tv = Tp[(size_t)n * NMODES];            // coalesced vector load
#pragma unroll
        for (int r = 0; r < 8; ++r)
            acc[r] = fmaf(xp[(size_t)r * N_LEN + n], tv, acc[r]); // uniform -> s_load
    }

#pragma unroll
    for (int r = 0; r < 8; ++r)
        atomicAdd(&xm[(size_t)(row0 + r) * NMODES + lane], acc[r]);
}

// ---------------------------------------------------------------------------
// Mix: z[b][o][k] = sin(pw[0][o][k]) *
//      sum_i xm[b][i][k]*ye[i][o][k] + xm[b][i][kf]*yo[i][o][k]
// where kf=(64-k)&63, ye=0.5(w+wf), yo=0.5(w-wf). Tiny kernel.
// Grid: (b=32, og=8), block 256 = 4 o's x 64 k-lanes.
// ---------------------------------------------------------------------------
__global__ __launch_bounds__(256) void mixk(const float* __restrict__ xm,
                                            const float* __restrict__ w1,
                                            const float* __restrict__ pw,
                                            float* __restrict__ z) {
    int k = threadIdx.x & 63;
    int wave = (int)__builtin_amdgcn_readfirstlane((int)(threadIdx.x >> 6));
    int b = blockIdx.x;
    int o = blockIdx.y * 4 + wave;
    int kf = (NMODES - k) & 63;

    float acc = 0.f;
#pragma unroll 4
    for (int i = 0; i < 32; ++i) {
        float xv  = xm[(size_t)(b * 32 + i) * NMODES + k];
        float xvf = xm[(size_t)(b * 32 + i) * NMODES + kf];
        float w   = w1[(size_t)(i * 32 + o) * NMODES + k];
        float wf  = w1[(size_t)(i * 32 + o) * NMODES + kf];
        acc = fmaf(xv, 0.5f * (w + wf), acc);
        acc = fmaf(xvf, 0.5f * (w - wf), acc);
    }
    z[(size_t)(b * 32 + o) * NMODES + k] = acc * sinf(pw[(size_t)o * NMODES + k]);
}

// ---------------------------------------------------------------------------
// GEMM2: out[row][n] = (1/N) * sum_k z[row][k] * Tt[k][n]
// lanes = n (float4 per lane -> 256 n per wave). Each wave: 16 rows.
// z values are wave-uniform -> scalar loads. Coalesced float4 stores.
// Grid: (64 row groups of 16) x (16 n-groups of 1024 = 4 waves x 256).
// ---------------------------------------------------------------------------
__global__ __launch_bounds__(256) void gemm2(const float* __restrict__ ws,
                                             float* __restrict__ out) {
    const float* Tt = ws + TT_OFF;
    const float* z  = ws + Z_OFF;
    int lane = threadIdx.x & 63;
    int wave = (int)__builtin_amdgcn_readfirstlane((int)(threadIdx.x >> 6));
    int row0 = blockIdx.x * 16;
    int nb   = blockIdx.y * 1024 + wave * 256 + 4 * lane;

    float4 acc[16];
#pragma unroll
    for (int r = 0; r < 16; ++r) acc[r] = make_float4(0.f, 0.f, 0.f, 0.f);

#pragma unroll 4
    for (int k = 0; k < NMODES; ++k) {
        float4 tv = *(const float4*)(Tt + (size_t)k * N_LEN + nb);
#pragma unroll
        for (int r = 0; r < 16; ++r) {
            float zv = z[(size_t)(row0 + r) * NMODES + k];  // uniform -> s_load
            acc[r].x = fmaf(zv, tv.x, acc[r].x);
            acc[r].y = fmaf(zv, tv.y, acc[r].y);
            acc[r].z = fmaf(zv, tv.z, acc[r].z);
            acc[r].w = fmaf(zv, tv.w, acc[r].w);
        }
    }

    const float sc = 1.0f / (float)N_LEN;
#pragma unroll
    for (int r = 0; r < 16; ++r) {
        float4 v = make_float4(acc[r].x * sc, acc[r].y * sc, acc[r].z * sc, acc[r].w * sc);
        *(float4*)(out + (size_t)(row0 + r) * N_LEN + nb) = v;
    }
}

// ---------------------------------------------------------------------------
extern "C" void kernel_launch(void* const* d_in, const int* in_sizes, int n_in,
                              void* d_out, int out_size, void* d_ws, size_t ws_size,
                              hipStream_t stream) {
    const float* x  = (const float*)d_in[0];   // (32, 32, 16384)
    const float* w1 = (const float*)d_in[1];   // (32, 32, 64)
    const float* pw = (const float*)d_in[2];   // (32, 32, 64)
    float* out = (float*)d_out;                // (32, 32, 16384)
    float* ws  = (float*)d_ws;

    // Zero the xm accumulator (ws is re-poisoned before every call).
    hipMemsetAsync(ws + XM_OFF, 0, (size_t)NROWS * NMODES * sizeof(float), stream);

    build_tables<<<dim3((2 * N_LEN * NMODES) / 256), dim3(256), 0, stream>>>(ws);

    gemm1<<<dim3(32, G1_KS), dim3(256), 0, stream>>>(x, ws + T_OFF, ws + XM_OFF);

    mixk<<<dim3(32, 8), dim3(256), 0, stream>>>(ws + XM_OFF, w1, pw, ws + Z_OFF);

    gemm2<<<dim3(64, 16), dim3(256), 0, stream>>>(ws, out);
}

// Round 2
// 225.589 us; speedup vs baseline: 1.7366x; 1.7366x over previous
//
#include <hip/hip_runtime.h>
#include <math.h>

// Problem constants
#define N_LEN 16384
#define NMODES 64
#define NROWS 1024          // B*C = 32*32
#define TWO_PI_OVER_N 3.8349519697141029e-04f

// ws layout (in floats)
#define T_OFF   0                         // T[n][k], 16384*64
#define TT_OFF  (N_LEN * NMODES)          // Tt[k][n], 64*16384
#define XM_OFF  (2 * N_LEN * NMODES)      // xm[row][k], 1024*64
#define Z_OFF   (XM_OFF + NROWS * NMODES) // z[row][k], 1024*64

// ---------------------------------------------------------------------------
// Build cas tables: T[n][k] = cas(2*pi*n*k/N), Tt[k][n] = transposed layout.
// ---------------------------------------------------------------------------
__global__ __launch_bounds__(256) void build_tables(float* __restrict__ ws) {
    int idx = blockIdx.x * 256 + threadIdx.x;   // 0 .. 2*1048576-1
    float* T  = ws + T_OFF;
    float* Tt = ws + TT_OFF;
    if (idx < N_LEN * NMODES) {
        int n = idx >> 6, k = idx & 63;
        int r = (n * k) & (N_LEN - 1);
        float th = (float)r * TWO_PI_OVER_N;
        float s, c;
        sincosf(th, &s, &c);
        T[idx] = c + s;
    } else {
        int j = idx - N_LEN * NMODES;
        int k = j >> 14, n = j & (N_LEN - 1);
        int r = (n * k) & (N_LEN - 1);
        float th = (float)r * TWO_PI_OVER_N;
        float s, c;
        sincosf(th, &s, &c);
        Tt[j] = c + s;
    }
}

// ---------------------------------------------------------------------------
// GEMM1: xm[row][k] = sum_n x[row][n] * T[n][k]
// Block: 64 rows x 64 modes, K-split 32 (chunk 512 n). Grid (16, 32).
// x tile (64 rows x 64 n = 16 KB) staged in LDS via coalesced float4 loads;
// inner loop: ds_read_b128 broadcast (same addr across lanes) + coalesced
// T loads. Partials combined with fp32 atomicAdd (xm zeroed beforehand).
// ---------------------------------------------------------------------------
#define G1_RB 64
#define G1_KSPLIT 32
#define G1_CHUNK (N_LEN / G1_KSPLIT)   // 512
#define G1_TILE 64

__global__ __launch_bounds__(256) void gemm1(const float* __restrict__ x,
                                             const float* __restrict__ T,
                                             float* __restrict__ xm) {
    __shared__ float xt[G1_RB * G1_TILE];   // 16 KB
    const int tid  = threadIdx.x;
    const int lane = tid & 63;              // mode index k
    const int wave = tid >> 6;              // 4 waves -> 16 rows each
    const int row0 = blockIdx.x * G1_RB;
    const int n0   = blockIdx.y * G1_CHUNK;

    float acc[16];
#pragma unroll
    for (int r = 0; r < 16; ++r) acc[r] = 0.f;

    for (int c = 0; c < G1_CHUNK / G1_TILE; ++c) {   // 8 tiles
        const int nc = n0 + c * G1_TILE;
        // stage: 64 rows x 64 n. 16 lanes cover one 256B row segment.
#pragma unroll
        for (int j = 0; j < 4; ++j) {
            int f   = (j * 256 + tid) * 4;
            int row = f >> 6;
            int nn  = f & 63;
            float4 v = *(const float4*)(x + (size_t)(row0 + row) * N_LEN + nc + nn);
            *(float4*)(xt + f) = v;
        }
        __syncthreads();

        const float* Trow = T + (size_t)nc * NMODES + lane;
#pragma unroll 2
        for (int g = 0; g < 16; ++g) {       // 4 n per group
            float tv0 = Trow[(size_t)(g * 4 + 0) * NMODES];
            float tv1 = Trow[(size_t)(g * 4 + 1) * NMODES];
            float tv2 = Trow[(size_t)(g * 4 + 2) * NMODES];
            float tv3 = Trow[(size_t)(g * 4 + 3) * NMODES];
#pragma unroll
            for (int r = 0; r < 16; ++r) {
                float4 xv = *(const float4*)(xt + (wave * 16 + r) * G1_TILE + g * 4);
                acc[r] = fmaf(xv.x, tv0, acc[r]);
                acc[r] = fmaf(xv.y, tv1, acc[r]);
                acc[r] = fmaf(xv.z, tv2, acc[r]);
                acc[r] = fmaf(xv.w, tv3, acc[r]);
            }
        }
        __syncthreads();
    }

#pragma unroll
    for (int r = 0; r < 16; ++r)
        atomicAdd(&xm[(size_t)(row0 + wave * 16 + r) * NMODES + lane], acc[r]);
}

// ---------------------------------------------------------------------------
// Mix: z[b][o][k] = (1/N) * sin(pw[0][o][k]) *
//      sum_i xm[b][i][k]*ye + xm[b][i][kf]*yo,  kf=(64-k)&63
// Grid: (b=32, og=8), block 256 = 4 o's x 64 k-lanes. 1/N folded here.
// ---------------------------------------------------------------------------
__global__ __launch_bounds__(256) void mixk(const float* __restrict__ xm,
                                            const float* __restrict__ w1,
                                            const float* __restrict__ pw,
                                            float* __restrict__ z) {
    int k = threadIdx.x & 63;
    int wave = threadIdx.x >> 6;
    int b = blockIdx.x;
    int o = blockIdx.y * 4 + wave;
    int kf = (NMODES - k) & 63;

    float acc = 0.f;
#pragma unroll 4
    for (int i = 0; i < 32; ++i) {
        float xv  = xm[(size_t)(b * 32 + i) * NMODES + k];
        float xvf = xm[(size_t)(b * 32 + i) * NMODES + kf];
        float w   = w1[(size_t)(i * 32 + o) * NMODES + k];
        float wf  = w1[(size_t)(i * 32 + o) * NMODES + kf];
        acc = fmaf(xv, 0.5f * (w + wf), acc);
        acc = fmaf(xvf, 0.5f * (w - wf), acc);
    }
    const float sc = 1.0f / (float)N_LEN;
    z[(size_t)(b * 32 + o) * NMODES + k] = acc * sinf(pw[(size_t)o * NMODES + k]) * sc;
}

// ---------------------------------------------------------------------------
// GEMM2: out[row][n] = sum_k z[row][k] * Tt[k][n]   (1/N already in z)
// Block: 16 rows x 1024 n (4 waves x 64 lanes x float4). Grid (64, 16).
// z tile (16x64 = 4 KB) staged once in LDS; ds_read_b128 broadcast inner.
// ---------------------------------------------------------------------------
__global__ __launch_bounds__(256) void gemm2(const float* __restrict__ Tt,
                                             const float* __restrict__ z,
                                             float* __restrict__ out) {
    __shared__ float zs[16 * NMODES];       // 4 KB
    const int tid  = threadIdx.x;
    const int lane = tid & 63;
    const int wave = tid >> 6;
    const int row0 = blockIdx.x * 16;
    const int nb   = blockIdx.y * 1024 + wave * 256 + lane * 4;

    // stage z[16][64] coalesced
#pragma unroll
    for (int j = 0; j < 4; ++j)
        zs[j * 256 + tid] = z[(size_t)row0 * NMODES + j * 256 + tid];
    __syncthreads();

    float4 acc[16];
#pragma unroll
    for (int r = 0; r < 16; ++r) acc[r] = make_float4(0.f, 0.f, 0.f, 0.f);

    for (int g = 0; g < 16; ++g) {          // 4 k per group
        float4 tv0 = *(const float4*)(Tt + (size_t)(g * 4 + 0) * N_LEN + nb);
        float4 tv1 = *(const float4*)(Tt + (size_t)(g * 4 + 1) * N_LEN + nb);
        float4 tv2 = *(const float4*)(Tt + (size_t)(g * 4 + 2) * N_LEN + nb);
        float4 tv3 = *(const float4*)(Tt + (size_t)(g * 4 + 3) * N_LEN + nb);
#pragma unroll
        for (int r = 0; r < 16; ++r) {
            float4 zv = *(const float4*)(zs + r * NMODES + g * 4);
            acc[r].x = fmaf(zv.x, tv0.x, acc[r].x);
            acc[r].y = fmaf(zv.x, tv0.y, acc[r].y);
            acc[r].z = fmaf(zv.x, tv0.z, acc[r].z);
            acc[r].w = fmaf(zv.x, tv0.w, acc[r].w);
            acc[r].x = fmaf(zv.y, tv1.x, acc[r].x);
            acc[r].y = fmaf(zv.y, tv1.y, acc[r].y);
            acc[r].z = fmaf(zv.y, tv1.z, acc[r].z);
            acc[r].w = fmaf(zv.y, tv1.w, acc[r].w);
            acc[r].x = fmaf(zv.z, tv2.x, acc[r].x);
            acc[r].y = fmaf(zv.z, tv2.y, acc[r].y);
            acc[r].z = fmaf(zv.z, tv2.z, acc[r].z);
            acc[r].w = fmaf(zv.z, tv2.w, acc[r].w);
            acc[r].x = fmaf(zv.w, tv3.x, acc[r].x);
            acc[r].y = fmaf(zv.w, tv3.y, acc[r].y);
            acc[r].z = fmaf(zv.w, tv3.z, acc[r].z);
            acc[r].w = fmaf(zv.w, tv3.w, acc[r].w);
        }
    }

#pragma unroll
    for (int r = 0; r < 16; ++r)
        *(float4*)(out + (size_t)(row0 + r) * N_LEN + nb) = acc[r];
}

// ---------------------------------------------------------------------------
extern "C" void kernel_launch(void* const* d_in, const int* in_sizes, int n_in,
                              void* d_out, int out_size, void* d_ws, size_t ws_size,
                              hipStream_t stream) {
    const float* x  = (const float*)d_in[0];   // (32, 32, 16384)
    const float* w1 = (const float*)d_in[1];   // (32, 32, 64)
    const float* pw = (const float*)d_in[2];   // (32, 32, 64)
    float* out = (float*)d_out;                // (32, 32, 16384)
    float* ws  = (float*)d_ws;

    // Zero the xm accumulator (ws is re-poisoned before every call).
    hipMemsetAsync(ws + XM_OFF, 0, (size_t)NROWS * NMODES * sizeof(float), stream);

    build_tables<<<dim3((2 * N_LEN * NMODES) / 256), dim3(256), 0, stream>>>(ws);

    gemm1<<<dim3(16, G1_KSPLIT), dim3(256), 0, stream>>>(x, ws + T_OFF, ws + XM_OFF);

    mixk<<<dim3(32, 8), dim3(256), 0, stream>>>(ws + XM_OFF, w1, pw, ws + Z_OFF);

    gemm2<<<dim3(64, 16), dim3(256), 0, stream>>>(ws + TT_OFF, ws + Z_OFF, out);
}